// Round 1
// 951.460 us; speedup vs baseline: 1.3826x; 1.3826x over previous
//
#include <hip/hip_runtime.h>

#define NN 50000
#define LL 4
#define DD 128
#define KDIM 16
#define EE 800000
#define MM (NN * LL)
#define DECAYF 0.7f
#define EPSF 1e-5f
#define SCAN_CHUNK 512
#define SCAN_NBLK ((NN + SCAN_CHUNK - 1) / SCAN_CHUNK)   // 98

typedef __attribute__((ext_vector_type(8))) short s16x8;   // 8 bf16 (4 VGPRs) MFMA frag
typedef __attribute__((ext_vector_type(4))) float fx4;     // MFMA accumulator

// ---------- bf16 split helpers (RNE) ----------
__device__ __forceinline__ short f2bf(float x) {
    unsigned u = __float_as_uint(x);
    u += 0x7fffu + ((u >> 16) & 1u);
    return (short)(u >> 16);
}
__device__ __forceinline__ float bf2f(short h) {
    return __uint_as_float(((unsigned)(unsigned short)h) << 16);
}

// ---------- CSR build ----------
__global__ void k_zero(int* p, int n) {
    int i = blockIdx.x * 256 + threadIdx.x;
    if (i < n) p[i] = 0;
}
__global__ void k_hist(const int* __restrict__ rows, int* __restrict__ counts) {
    int e = blockIdx.x * 256 + threadIdx.x;
    if (e < EE) atomicAdd(&counts[rows[e]], 1);
}
__global__ void k_scan1(const int* __restrict__ counts, int* __restrict__ offs, int* __restrict__ csum) {
    __shared__ int s[SCAN_CHUNK];
    int i = blockIdx.x * SCAN_CHUNK + threadIdx.x;
    int v = (i < NN) ? counts[i] : 0;
    s[threadIdx.x] = v;
    __syncthreads();
    for (int off = 1; off < SCAN_CHUNK; off <<= 1) {
        int t = (threadIdx.x >= off) ? s[threadIdx.x - off] : 0;
        __syncthreads();
        s[threadIdx.x] += t;
        __syncthreads();
    }
    if (i < NN) offs[i] = s[threadIdx.x] - v;
    if (threadIdx.x == SCAN_CHUNK - 1) csum[blockIdx.x] = s[SCAN_CHUNK - 1];
}
__global__ void k_scan2(int* __restrict__ csum) {
    __shared__ int s[128];
    int v = (threadIdx.x < SCAN_NBLK) ? csum[threadIdx.x] : 0;
    s[threadIdx.x] = v;
    __syncthreads();
    for (int off = 1; off < 128; off <<= 1) {
        int t = (threadIdx.x >= off) ? s[threadIdx.x - off] : 0;
        __syncthreads();
        s[threadIdx.x] += t;
        __syncthreads();
    }
    if (threadIdx.x < SCAN_NBLK) csum[threadIdx.x] = s[threadIdx.x] - v;
}
__global__ void k_scan3(int* __restrict__ offs, const int* __restrict__ csum, int* __restrict__ cursor) {
    int i = blockIdx.x * SCAN_CHUNK + threadIdx.x;
    if (i < NN) {
        int v = offs[i] + csum[blockIdx.x];
        offs[i] = v;
        cursor[i] = v;
    } else if (i == NN) {
        offs[NN] = EE;
    }
}
__global__ void k_fill(const int* __restrict__ rows, const int* __restrict__ cols,
                       const float* __restrict__ vals,
                       int* __restrict__ cursor, int* __restrict__ ccol, float* __restrict__ cval) {
    int e = blockIdx.x * 256 + threadIdx.x;
    if (e < EE) {
        int r = rows[e];
        int pos = atomicAdd(&cursor[r], 1);
        ccol[pos] = cols[e];
        cval[pos] = vals[e];
    }
}

// ---------- SAGE aggregation -> io (f32) ----------
__global__ __launch_bounds__(128) void k_agg(const int* __restrict__ offs, const int* __restrict__ ccol,
                                             const float* __restrict__ cval,
                                             const float* __restrict__ x,
                                             float* __restrict__ agg) {
    int n = blockIdx.x;
    int tid = threadIdx.x;    // = d
    int s = offs[n], e = offs[n + 1];
    float a0 = 0.f, a1 = 0.f, a2 = 0.f, a3 = 0.f;
    for (int p = s; p < e; p++) {
        int c = ccol[p];
        float w = cval[p];
        a0 += w * x[((size_t)(0 * NN + c)) * DD + tid];
        a1 += w * x[((size_t)(1 * NN + c)) * DD + tid];
        a2 += w * x[((size_t)(2 * NN + c)) * DD + tid];
        a3 += w * x[((size_t)(3 * NN + c)) * DD + tid];
    }
    agg[((size_t)(0 * NN + n)) * DD + tid] = a0;
    agg[((size_t)(1 * NN + n)) * DD + tid] = a1;
    agg[((size_t)(2 * NN + n)) * DD + tid] = a2;
    agg[((size_t)(3 * NN + n)) * DD + tid] = a3;
}

// ---------- weight prep: transpose + bf16 hi/lo split ----------
// out layout (shorts): sWh[16384] sWl aWh aWl vWh vWl | l1h[32768] l1l | l2h[16384] l2l
__global__ void k_wprep(const float* __restrict__ sW, const float* __restrict__ aW,
                        const float* __restrict__ vW, const float* __restrict__ w1,
                        const float* __restrict__ w2, short* __restrict__ out) {
    int b = blockIdx.x;   // 384 blocks x 256 threads
    const float* src; short* h; short* l; int K; int base;
    if (b < 64)       { src = sW; h = out;          l = out + 16384;  K = 128; base = b; }
    else if (b < 128) { src = aW; h = out + 32768;  l = out + 49152;  K = 128; base = b - 64; }
    else if (b < 192) { src = vW; h = out + 65536;  l = out + 81920;  K = 128; base = b - 128; }
    else if (b < 320) { src = w1; h = out + 98304;  l = out + 131072; K = 256; base = b - 192; }
    else              { src = w2; h = out + 163840; l = out + 180224; K = 128; base = b - 320; }
    int idx = base * 256 + threadIdx.x;   // over K*128, row-major [K][128]
    int k = idx >> 7, n = idx & 127;
    float v = src[idx];
    short hh = f2bf(v);
    h[n * K + k] = hh;                    // transposed: [n][K]
    l[n * K + k] = f2bf(v - bf2f(hh));
}

// ---------- stage 64x128 f32 rows -> LDS bf16 hi/lo tiles, row stride 136 ----------
__device__ __forceinline__ void stage64(const float* __restrict__ src, int rowbase,
                                        short* __restrict__ h, short* __restrict__ l, int tid) {
    int row = tid >> 2, ko = (tid & 3) * 32;
    const float* gp = src + (size_t)(rowbase + row) * DD + ko;
    short* dh = h + row * 136 + ko;
    short* dl = l + row * 136 + ko;
    #pragma unroll
    for (int j = 0; j < 4; j++) {
        float4 a = *reinterpret_cast<const float4*>(gp + j * 8);
        float4 b = *reinterpret_cast<const float4*>(gp + j * 8 + 4);
        float v[8] = {a.x, a.y, a.z, a.w, b.x, b.y, b.z, b.w};
        s16x8 hv, lv;
        #pragma unroll
        for (int e = 0; e < 8; e++) {
            short hh = f2bf(v[e]);
            hv[e] = hh;
            lv[e] = f2bf(v[e] - bf2f(hh));
        }
        *(s16x8*)(dh + j * 8) = hv;
        *(s16x8*)(dl + j * 8) = lv;
    }
}

// ---------- one 64x128 (M x N) GEMM pass, K=128, bf16x3 split MFMA ----------
// A (hi/lo) in LDS [64][136]; B = W^T (hi/lo) in global [128][wlen], k-offset koff.
// k bijection (ks*32 + kg*8 + i) identical on A and B frags -> dot order-independent.
// C/D layout [m89]: col = lane&15, row = (lane>>4)*4 + reg.
__device__ __forceinline__ void mfma_pass(const short* __restrict__ a0, const short* __restrict__ a1,
                                          const short* __restrict__ Wh, const short* __restrict__ Wl,
                                          int wlen, int koff, int w, int l16, int kg,
                                          fx4 acc[4][2]) {
    #pragma unroll
    for (int ks = 0; ks < 4; ks++) {
        s16x8 ah[4], al[4];
        #pragma unroll
        for (int mt = 0; mt < 4; mt++) {
            int ao = (mt * 16 + l16) * 136 + ks * 32 + kg * 8;
            ah[mt] = *(const s16x8*)(a0 + ao);
            al[mt] = *(const s16x8*)(a1 + ao);
        }
        #pragma unroll
        for (int nt = 0; nt < 2; nt++) {
            int col = w * 32 + nt * 16 + l16;
            int bo = col * wlen + koff + ks * 32 + kg * 8;
            s16x8 bh = *(const s16x8*)(Wh + bo);
            s16x8 bl = *(const s16x8*)(Wl + bo);
            #pragma unroll
            for (int mt = 0; mt < 4; mt++) {
                acc[mt][nt] = __builtin_amdgcn_mfma_f32_16x16x32_bf16(ah[mt], bh, acc[mt][nt], 0, 0, 0);
                acc[mt][nt] = __builtin_amdgcn_mfma_f32_16x16x32_bf16(ah[mt], bl, acc[mt][nt], 0, 0, 0);
                acc[mt][nt] = __builtin_amdgcn_mfma_f32_16x16x32_bf16(al[mt], bh, acc[mt][nt], 0, 0, 0);
            }
        }
    }
}

// ---------- fused (1|2)x GEMM [64x128,K=128] + bias/res/silu + LayerNorm ----------
// In-place (out_ aliasing in1_/in2_/res rows of this block) is safe: all global reads
// complete behind __syncthreads() before the epilogue writes.
template <int NIN, bool RES>
__global__ __launch_bounds__(256, 4) void k_fused(
    const float* __restrict__ in1_, const short* __restrict__ W1h, const short* __restrict__ W1l,
    const float* __restrict__ in2_, const short* __restrict__ W2h, const short* __restrict__ W2l,
    const float* __restrict__ res_, const float* __restrict__ bias,
    const float* __restrict__ g, const float* __restrict__ bb,
    float* __restrict__ out_) {
    __shared__ __align__(16) short stg[2][64 * 136];   // 34816 B; f32 LN scratch aliases it
    float* fscr = (float*)&stg[0][0];                  // [64][129] = 33024 B
    const int rowbase = blockIdx.x * 64;
    const int tid = threadIdx.x;
    const int w = tid >> 6, lane = tid & 63;
    const int l16 = lane & 15, kg = lane >> 4;

    fx4 acc[4][2];
    #pragma unroll
    for (int mt = 0; mt < 4; mt++)
        #pragma unroll
        for (int nt = 0; nt < 2; nt++) acc[mt][nt] = (fx4){0.f, 0.f, 0.f, 0.f};

    #pragma unroll
    for (int pass = 0; pass < NIN; pass++) {
        const float* in_ = (pass == 0) ? in1_ : in2_;
        const short* Wh  = (pass == 0) ? W1h : W2h;
        const short* Wl  = (pass == 0) ? W1l : W2l;
        stage64(in_, rowbase, &stg[0][0], &stg[1][0], tid);
        __syncthreads();
        mfma_pass(&stg[0][0], &stg[1][0], Wh, Wl, 128, 0, w, l16, kg, acc);
        __syncthreads();
    }

    float bias_r[2];
    #pragma unroll
    for (int nt = 0; nt < 2; nt++) bias_r[nt] = bias[w * 32 + nt * 16 + l16];
    #pragma unroll
    for (int mt = 0; mt < 4; mt++) {
        #pragma unroll
        for (int r = 0; r < 4; r++) {
            int row = mt * 16 + kg * 4 + r;
            size_t m = (size_t)rowbase + row;
            #pragma unroll
            for (int nt = 0; nt < 2; nt++) {
                int col = w * 32 + nt * 16 + l16;
                float y = acc[mt][nt][r] + bias_r[nt];
                if (RES) y += res_[m * DD + col];
                y = y / (1.f + expf(-y));
                fscr[row * 129 + col] = y;
            }
        }
    }
    __syncthreads();
    {
        float g0 = g[lane], g1 = g[64 + lane];
        float b0 = bb[lane], b1 = bb[64 + lane];
        #pragma unroll 1
        for (int rr = 0; rr < 16; rr++) {
            int row = w * 16 + rr;
            size_t m = (size_t)rowbase + row;
            float y0 = fscr[row * 129 + lane], y1 = fscr[row * 129 + 64 + lane];
            float s = y0 + y1, q = y0 * y0 + y1 * y1;
            #pragma unroll
            for (int off = 32; off; off >>= 1) {
                s += __shfl_xor(s, off, 64);
                q += __shfl_xor(q, off, 64);
            }
            float mean = s * (1.f / 128.f);
            float var = fmaxf(q * (1.f / 128.f) - mean * mean, 0.f);
            float rstd = rsqrtf(var + EPSF);
            out_[m * DD + lane]      = (y0 - mean) * rstd * g0 + b0;
            out_[m * DD + 64 + lane] = (y1 - mean) * rstd * g1 + b1;
        }
    }
}

// ---------- lin1 with inline att branch (MFMA) ----------
// atile = LN((x@Wv) * w) as bf16 hi/lo in LDS, then
// h1 = LN(silu(sage@W1[0:128] + atile@W1[128:256] + b)) -> sage_io.
__global__ __launch_bounds__(256, 2) void k_lin1(
    const float* __restrict__ x,
    const short* __restrict__ Wvh, const short* __restrict__ Wvl,
    const float* __restrict__ wtbuf,
    const float* __restrict__ att_g, const float* __restrict__ att_b,
    float* __restrict__ sage_io,
    const short* __restrict__ W1h, const short* __restrict__ W1l,   // [128][256] transposed
    const float* __restrict__ bias,
    const float* __restrict__ g, const float* __restrict__ bb) {
    __shared__ __align__(16) short stg[2][64 * 136];   // staging + f32 LN scratch alias
    __shared__ __align__(16) short atl[2][64 * 136];   // att LN output, persists
    float* fscr = (float*)&stg[0][0];
    const int rowbase = blockIdx.x * 64;
    const int tid = threadIdx.x;
    const int w = tid >> 6, lane = tid & 63;
    const int l16 = lane & 15, kg = lane >> 4;

    fx4 acc[4][2];
    #pragma unroll
    for (int mt = 0; mt < 4; mt++)
        #pragma unroll
        for (int nt = 0; nt < 2; nt++) acc[mt][nt] = (fx4){0.f, 0.f, 0.f, 0.f};

    // ---- att: x @ Wv ----
    stage64(x, rowbase, &stg[0][0], &stg[1][0], tid);
    __syncthreads();
    mfma_pass(&stg[0][0], &stg[1][0], Wvh, Wvl, 128, 0, w, l16, kg, acc);
    __syncthreads();   // all A-frag reads of stg done before fscr overwrite

    #pragma unroll
    for (int mt = 0; mt < 4; mt++) {
        #pragma unroll
        for (int r = 0; r < 4; r++) {
            int row = mt * 16 + kg * 4 + r;
            size_t m = (size_t)rowbase + row;
            int l = (int)(m / NN), n = (int)(m % NN);
            float ws = wtbuf[n * LL + l];
            #pragma unroll
            for (int nt = 0; nt < 2; nt++) {
                int col = w * 32 + nt * 16 + l16;
                fscr[row * 129 + col] = acc[mt][nt][r] * ws;
            }
        }
    }
    __syncthreads();
    {   // att LN -> atl (bf16 hi/lo, stride 136)
        float g0 = att_g[lane], g1 = att_g[64 + lane];
        float b0 = att_b[lane], b1 = att_b[64 + lane];
        #pragma unroll 1
        for (int rr = 0; rr < 16; rr++) {
            int row = w * 16 + rr;
            float y0 = fscr[row * 129 + lane], y1 = fscr[row * 129 + 64 + lane];
            float s = y0 + y1, q = y0 * y0 + y1 * y1;
            #pragma unroll
            for (int off = 32; off; off >>= 1) {
                s += __shfl_xor(s, off, 64);
                q += __shfl_xor(q, off, 64);
            }
            float mean = s * (1.f / 128.f);
            float var = fmaxf(q * (1.f / 128.f) - mean * mean, 0.f);
            float rstd = rsqrtf(var + EPSF);
            float z0 = (y0 - mean) * rstd * g0 + b0;
            float z1 = (y1 - mean) * rstd * g1 + b1;
            short h0 = f2bf(z0), h1 = f2bf(z1);
            atl[0][row * 136 + lane]      = h0;
            atl[1][row * 136 + lane]      = f2bf(z0 - bf2f(h0));
            atl[0][row * 136 + 64 + lane] = h1;
            atl[1][row * 136 + 64 + lane] = f2bf(z1 - bf2f(h1));
        }
    }
    __syncthreads();   // fscr reads done before restage

    // ---- h1 = sage @ W1[:,0:128] + atile @ W1[:,128:256] ----
    stage64(sage_io, rowbase, &stg[0][0], &stg[1][0], tid);
    #pragma unroll
    for (int mt = 0; mt < 4; mt++)
        #pragma unroll
        for (int nt = 0; nt < 2; nt++) acc[mt][nt] = (fx4){0.f, 0.f, 0.f, 0.f};
    __syncthreads();
    mfma_pass(&stg[0][0], &stg[1][0], W1h, W1l, 256, 0, w, l16, kg, acc);
    mfma_pass(&atl[0][0], &atl[1][0], W1h, W1l, 256, 128, w, l16, kg, acc);
    __syncthreads();

    float bias_r[2];
    #pragma unroll
    for (int nt = 0; nt < 2; nt++) bias_r[nt] = bias[w * 32 + nt * 16 + l16];
    #pragma unroll
    for (int mt = 0; mt < 4; mt++) {
        #pragma unroll
        for (int r = 0; r < 4; r++) {
            int row = mt * 16 + kg * 4 + r;
            #pragma unroll
            for (int nt = 0; nt < 2; nt++) {
                int col = w * 32 + nt * 16 + l16;
                float y = acc[mt][nt][r] + bias_r[nt];
                y = y / (1.f + expf(-y));
                fscr[row * 129 + col] = y;
            }
        }
    }
    __syncthreads();
    {
        float g0 = g[lane], g1 = g[64 + lane];
        float b0 = bb[lane], b1 = bb[64 + lane];
        #pragma unroll 1
        for (int rr = 0; rr < 16; rr++) {
            int row = w * 16 + rr;
            size_t m = (size_t)rowbase + row;
            float y0 = fscr[row * 129 + lane], y1 = fscr[row * 129 + 64 + lane];
            float s = y0 + y1, q = y0 * y0 + y1 * y1;
            #pragma unroll
            for (int off = 32; off; off >>= 1) {
                s += __shfl_xor(s, off, 64);
                q += __shfl_xor(q, off, 64);
            }
            float mean = s * (1.f / 128.f);
            float var = fmaxf(q * (1.f / 128.f) - mean * mean, 0.f);
            float rstd = rsqrtf(var + EPSF);
            sage_io[m * DD + lane]      = (y0 - mean) * rstd * g0 + b0;
            sage_io[m * DD + 64 + lane] = (y1 - mean) * rstd * g1 + b1;
        }
    }
}

// ---------- k,q projection + weights0 = mean(k*q) ----------
__global__ __launch_bounds__(256) void k_kq(const float* __restrict__ x,
                                            const float* __restrict__ Wk,
                                            const float* __restrict__ Wq,
                                            float* __restrict__ wt_total, float* __restrict__ iw0) {
    __shared__ float xt[64 * 129];
    __shared__ float kw[128 * 32];   // cols 0..15 = Wk, 16..31 = Wq
    int rowbase = blockIdx.x * 64;
    for (int t = threadIdx.x; t < 1024; t += 256) {
        int row = t >> 4;
        int co = (t & 15) * 8;
        float4 a = *reinterpret_cast<const float4*>(&x[(size_t)(rowbase + row) * DD + co]);
        float4 b = *reinterpret_cast<const float4*>(&x[(size_t)(rowbase + row) * DD + co + 4]);
        float* d = &xt[row * 129 + co];
        d[0] = a.x; d[1] = a.y; d[2] = a.z; d[3] = a.w;
        d[4] = b.x; d[5] = b.y; d[6] = b.z; d[7] = b.w;
    }
    {
        int t = threadIdx.x;
        int k = t >> 1, jh = (t & 1) * 8;
        #pragma unroll
        for (int j = 0; j < 8; j++) {
            kw[k * 32 + jh + j]      = Wk[(size_t)k * KDIM + jh + j];
            kw[k * 32 + 16 + jh + j] = Wq[(size_t)k * KDIM + jh + j];
        }
    }
    __syncthreads();
    int r = threadIdx.x & 63, grp = threadIdx.x >> 6;
    float acc[8];
    #pragma unroll
    for (int j = 0; j < 8; j++) acc[j] = 0.f;
    for (int k = 0; k < 128; k++) {
        float a = xt[r * 129 + k];
        float4 w0 = *reinterpret_cast<const float4*>(&kw[k * 32 + grp * 8]);
        float4 w1 = *reinterpret_cast<const float4*>(&kw[k * 32 + grp * 8 + 4]);
        acc[0] += a * w0.x; acc[1] += a * w0.y; acc[2] += a * w0.z; acc[3] += a * w0.w;
        acc[4] += a * w1.x; acc[5] += a * w1.y; acc[6] += a * w1.z; acc[7] += a * w1.w;
    }
    __syncthreads();
    float* yt = xt;   // reuse as [64][33]
    #pragma unroll
    for (int j = 0; j < 8; j++) yt[r * 33 + grp * 8 + j] = acc[j];
    __syncthreads();
    if (threadIdx.x < 64) {
        int row = threadIdx.x;
        float s = 0.f;
        #pragma unroll
        for (int j = 0; j < 16; j++) s += yt[row * 33 + j] * yt[row * 33 + 16 + j];
        s *= (1.f / 16.f);
        size_t m = (size_t)rowbase + row;
        int l = (int)(m / NN), n = (int)(m % NN);
        wt_total[n * LL + l] = s;
        iw0[n * LL + l] = s;
    }
}

// ---------- retentive weight iteration ----------
__global__ __launch_bounds__(256) void k_spmm_w(const int* __restrict__ offs, const int* __restrict__ ccol,
                                                const float* __restrict__ cval,
                                                const float* __restrict__ win, float* __restrict__ wout,
                                                float* __restrict__ wtot) {
    int i = blockIdx.x * 256 + threadIdx.x;
    if (i >= NN * LL) return;
    int n = i >> 2, l = i & 3;
    int s = offs[n], e = offs[n + 1];
    float a = 0.f;
    for (int p = s; p < e; p++) a += cval[p] * win[(ccol[p] << 2) | l];
    a *= DECAYF;
    wout[i] = a;
    wtot[i] += a;
}

extern "C" void kernel_launch(void* const* d_in, const int* in_sizes, int n_in,
                              void* d_out, int out_size, void* d_ws, size_t ws_size,
                              hipStream_t stream) {
    const float* x        = (const float*)d_in[0];
    const int*   ei       = (const int*)d_in[1];
    const float* evals    = (const float*)d_in[2];
    const float* sage_W   = (const float*)d_in[3];
    const float* sage_b   = (const float*)d_in[4];
    const float* sage_aggW= (const float*)d_in[5];
    const float* sage_ln_g= (const float*)d_in[6];
    const float* sage_ln_b= (const float*)d_in[7];
    const float* att_Wk   = (const float*)d_in[8];
    const float* att_Wq   = (const float*)d_in[9];
    const float* att_Wv   = (const float*)d_in[10];
    const float* att_ln_g = (const float*)d_in[11];
    const float* att_ln_b = (const float*)d_in[12];
    const float* lin1_W   = (const float*)d_in[13];
    const float* lin1_b   = (const float*)d_in[14];
    const float* lin2_W   = (const float*)d_in[15];
    const float* lin2_b   = (const float*)d_in[16];
    const float* ln1_g    = (const float*)d_in[17];
    const float* ln1_b    = (const float*)d_in[18];
    const float* ln2_g    = (const float*)d_in[19];
    const float* ln2_b    = (const float*)d_in[20];

    const int* rows = ei;
    const int* cols = ei + EE;

    // ---- workspace: ~9.8 MB ----
    float* wt_total = (float*)d_ws;                       // [N*L]
    float* iw0      = wt_total + MM;
    float* iw1      = iw0 + MM;
    float* cval     = iw1 + MM;                           // [E]
    int*   counts   = (int*)(cval + EE);                  // N
    int*   offs     = counts + NN;                        // N+1
    int*   cursor   = offs + NN + 1;                      // N
    int*   csum     = cursor + NN;                        // 128
    int*   ccol     = csum + 128;                         // E
    uintptr_t pw    = (uintptr_t)(ccol + EE);
    pw = (pw + 15) & ~(uintptr_t)15;
    short* wbf      = (short*)pw;                         // 196608 shorts (bf16 W^T hi/lo)
    float* io       = (float*)d_out;                      // [M,D] f32: agg -> sage -> h1 -> out

    // ---- weight transpose+split (independent of everything else) ----
    k_wprep<<<384, 256, 0, stream>>>(sage_W, sage_aggW, att_Wv, lin1_W, lin2_W, wbf);

    // ---- CSR build ----
    k_zero<<<(NN + 255) / 256, 256, 0, stream>>>(counts, NN);
    k_hist<<<(EE + 255) / 256, 256, 0, stream>>>(rows, counts);
    k_scan1<<<SCAN_NBLK, SCAN_CHUNK, 0, stream>>>(counts, offs, csum);
    k_scan2<<<1, 128, 0, stream>>>(csum);
    k_scan3<<<SCAN_NBLK, SCAN_CHUNK, 0, stream>>>(offs, csum, cursor);
    k_fill<<<(EE + 255) / 256, 256, 0, stream>>>(rows, cols, evals, cursor, ccol, cval);

    // ---- retentive weights ----
    k_kq<<<MM / 64, 256, 0, stream>>>(x, att_Wk, att_Wq, wt_total, iw0);
    k_spmm_w<<<(MM + 255) / 256, 256, 0, stream>>>(offs, ccol, cval, iw0, iw1, wt_total);
    k_spmm_w<<<(MM + 255) / 256, 256, 0, stream>>>(offs, ccol, cval, iw1, iw0, wt_total);

    // ---- SAGE aggregation -> io ----
    k_agg<<<NN, 128, 0, stream>>>(offs, ccol, cval, x, io);

    // ---- sage_out = LN(silu(x@W + b + agg@aggW)) -> io in-place ----
    k_fused<2, false><<<MM / 64, 256, 0, stream>>>(
        x, wbf, wbf + 16384, io, wbf + 32768, wbf + 49152,
        nullptr, sage_b, sage_ln_g, sage_ln_b, io);

    // ---- h1 = LN(silu(sage@W1a + LN((x@Wv)*w)@W1b + b)) -> io in-place ----
    k_lin1<<<MM / 64, 256, 0, stream>>>(
        x, wbf + 65536, wbf + 81920, wt_total, att_ln_g, att_ln_b, io,
        wbf + 98304, wbf + 131072, lin1_b, ln1_g, ln1_b);

    // ---- out = LN(silu(h1@lin2 + b + x)) -> io (= d_out) in-place ----
    k_fused<1, true><<<MM / 64, 256, 0, stream>>>(
        io, wbf + 163840, wbf + 180224, nullptr, nullptr, nullptr,
        x, lin2_b, ln2_g, ln2_b, io);

    (void)in_sizes; (void)n_in; (void)out_size; (void)ws_size;
}